// Round 5
// baseline (643.773 us; speedup 1.0000x reference)
//
#include <hip/hip_runtime.h>
#include <cstdint>
#include <cstddef>

#define TT 1000
#define NB 64000  // B*T

// ---------------------------------------------------------------------------
// NUMERICS CONTRACT: each z[n,o] is ONE ascending-k fp32 chain matching
// fmaf(s_k, W[k,o], acc), s_k in {0,1}. Exact identities used here:
//   fmaf(1,W,acc) == W + acc   (single rounding, identical)
//   fmaf(0,W,acc) == acc       (bitwise; acc is never -0: RN exact-zero
//                               sums give +0, chain starts at +0)
// => iterating ONLY active k ascending with v_add_f32 is bit-identical.
// Do not reorder k, do not tree-reduce.
//
// LEDGER: dense ladder r0-r4: busy-work invariant ~72us/gemm, idle ~30%
// immovable (occupancy r1, LDS-ratio r2, counted-vmcnt r3/r4 all failed;
// r4 fences cost VGPR 60->216). Dense is ~1.5x from floor => pivot to
// SPARSITY (r5): spikes -> bitmasks (ballot), scalar s_ff1 loop over
// active k, W o-half tile resident in LDS, zero in-loop barriers.
// ---------------------------------------------------------------------------

// ---------------------------------------------------------------------------
// Sparse GEMM: Z[r, bo:bo+OH] = sum_{k in mask(r)} Wlds[k, :]  (ascending k)
// Block: 1024 thr = 16 waves, one row per wave at a time. W tile K x OH f32
// in LDS, loaded once. Masks: KC u64 words per row, bit i of word c = k
// (c*64+i) active. Wave-uniform scalar loop (s_ff1), depth-2 LDS pipeline.
// ---------------------------------------------------------------------------
template <int K, int KC, int OH, int PO>
__global__ __launch_bounds__(1024) void spmm(
    const unsigned long long* __restrict__ M, const float* __restrict__ Wt,
    float* __restrict__ Z, int Wld, int Zld, int Ostore, int rowsPerBlock) {
  __shared__ float Wl[K * OH];
  const int tid = threadIdx.x;
  const int lane = tid & 63;
  const int bo = blockIdx.y * OH;

  // one-time W tile load (L2-resident source; grid reuses it)
  for (int i = tid; i < K * OH / 4; i += 1024) {
    int k = i / (OH / 4);
    int off = i - k * (OH / 4);
    *(float4*)&Wl[i * 4] = *(const float4*)&Wt[(size_t)k * Wld + bo + off * 4];
  }
  __syncthreads();

  const int wv = __builtin_amdgcn_readfirstlane(tid >> 6);
  const int r0 = blockIdx.x * rowsPerBlock;
  const int rend = r0 + rowsPerBlock;
  for (int r = r0 + wv; r < rend; r += 16) {
    const unsigned long long* mrow = M + (size_t)r * KC;
    float acc0 = 0.f, acc1 = 0.f;
#pragma unroll
    for (int c = 0; c < KC; c++) {
      unsigned long long m = mrow[c];
      if (m) {
        int kp = __builtin_ctzll(m);
        m &= m - 1;
        const float* wp = &Wl[(c * 64 + kp) * OH + lane * PO];
        float v0 = wp[0];
        float v1 = (PO == 2) ? wp[1] : 0.f;
        while (m) {
          int kn = __builtin_ctzll(m);
          m &= m - 1;
          const float* wn = &Wl[(c * 64 + kn) * OH + lane * PO];
          float u0 = wn[0];                       // issue next LDS load
          float u1 = (PO == 2) ? wn[1] : 0.f;
          acc0 += v0;                             // consume previous (asc. k)
          if (PO == 2) acc1 += v1;
          v0 = u0;
          v1 = u1;
        }
        acc0 += v0;
        if (PO == 2) acc1 += v1;
      }
    }
    int o0 = bo + lane * PO;
    float* zp = Z + (size_t)r * Zld + o0;
    if (PO == 2) {
      *(float2*)zp = make_float2(acc0, acc1);
    } else {
      if (o0 < Ostore) zp[0] = acc0;
    }
  }
}

// ---------------------------------------------------------------------------
// CUBA LIF recurrence (r12 pipeline: depth-2 x U=25, 50 outstanding loads).
// Exact per-step fp32 mul/add chain. Mid layers emit SPIKE BITMASKS:
// one u64 per wave per t via __ballot (bit i = lane i = o = chunk*64+i).
// ---------------------------------------------------------------------------
template <bool FINAL>
__global__ __launch_bounds__(64) void cuba_kernel(
    const float* __restrict__ Z, unsigned long long* __restrict__ Mout,
    float* __restrict__ Fout, unsigned int* __restrict__ cnt, int O,
    int total) {
  int gid = blockIdx.x * 64 + threadIdx.x;
  const int mchunk = blockIdx.x & 3;  // o-chunk within 256 (non-final only)
  unsigned int c = 0;
  if (gid < total) {
    int b = gid / O;
    int o = gid - b * O;
    const int nb = b * TT;
    const float* zp = Z + (size_t)nb * O + o;
    float* fp = Fout + ((size_t)b * O + o) * TT;
    float cur = 0.f, volt = 0.f;
    constexpr int U = 25;
    float z0[U], z1[U];

#define LOADB(buf, tbase)                         \
  _Pragma("unroll") for (int u = 0; u < U; u++) { \
    buf[u] = zp[(size_t)((tbase) + u) * O];       \
  }
#define COMPB(buf, tbase)                                              \
  _Pragma("unroll") for (int u = 0; u < U; u++) {                      \
    cur = __fadd_rn(__fmul_rn(0.75f, cur), buf[u]);                    \
    volt = __fadd_rn(__fmul_rn(0.97f, volt), cur);                     \
    bool fire = volt >= 1.25f;                                         \
    volt = fire ? 0.f : volt;                                          \
    c += fire ? 1u : 0u;                                               \
    if (FINAL) {                                                       \
      fp[(tbase) + u] = fire ? 1.f : 0.f;                              \
    } else {                                                           \
      unsigned long long mm = __ballot(fire);                          \
      if (threadIdx.x == 0)                                            \
        Mout[(size_t)(nb + (tbase) + u) * 4 + mchunk] = mm;            \
    }                                                                  \
  }

    LOADB(z0, 0)
    for (int i = 0; i < 20; i++) {
      const int base = i * 2 * U;
      LOADB(z1, base + U)
      COMPB(z0, base)
      if (i < 19) LOADB(z0, base + 2 * U)
      COMPB(z1, base + U)
    }
#undef LOADB
#undef COMPB
  }
#pragma unroll
  for (int off = 32; off; off >>= 1) c += __shfl_down(c, off, 64);
  if ((threadIdx.x & 63) == 0) atomicAdd(cnt, c);
}

// ---------------------------------------------------------------------------
// Fused prep: cnt zero + input bitmask + 4 weight transposes.
// ---------------------------------------------------------------------------
__device__ __forceinline__ void prep_w_item(const float* __restrict__ W,
                                            float* __restrict__ Wt, int O,
                                            int K, int Opad, int i) {
  int k = i / Opad, o = i - k * Opad;
  Wt[i] = (k < K && o < O) ? W[(size_t)o * K + k] : 0.f;
}

__global__ __launch_bounds__(256) void prep_all(
    const float* __restrict__ X, const float* __restrict__ W1,
    const float* __restrict__ W2, const float* __restrict__ W3,
    const float* __restrict__ W4, unsigned long long* __restrict__ Min,
    float* __restrict__ Wt1, float* __restrict__ Wt2,
    float* __restrict__ Wt3, float* __restrict__ Wt4,
    unsigned int* __restrict__ cnt) {
  const int blk = blockIdx.x;
  const int tid = threadIdx.x;
  if (blk == 0 && tid < 8) cnt[tid] = 0u;
  if (blk < 250) {
    int gid = blk * 256 + tid;  // n
    unsigned long long msk = 0ull;
#pragma unroll
    for (int ch = 0; ch < 20; ch++) {
      float v = X[((size_t)(gid / TT) * 20 + ch) * TT + (gid % TT)];
      msk |= (unsigned long long)(v != 0.f ? 1u : 0u) << ch;
    }
    Min[gid] = msk;
  } else if (blk < 270) {  // W1t [20][256]: 5120 items
    prep_w_item(W1, Wt1, 256, 20, 256, (blk - 250) * 256 + tid);
  } else if (blk < 526) {  // W2t [256][256]
    prep_w_item(W2, Wt2, 256, 256, 256, (blk - 270) * 256 + tid);
  } else if (blk < 782) {  // W3t [256][256]
    prep_w_item(W3, Wt3, 256, 256, 256, (blk - 526) * 256 + tid);
  } else {                 // W4t [256][64]: 16384 items
    prep_w_item(W4, Wt4, 35, 256, 64, (blk - 782) * 256 + tid);
  }
}

__global__ void finalize_counts(const unsigned int* __restrict__ cnt,
                                float* __restrict__ out) {
  int i = threadIdx.x;
  if (i < 4) {
    const float denom[4] = {16384000.f, 16384000.f, 16384000.f, 2240000.f};
    out[i] = (float)cnt[i] / denom[i];
  }
}

// ---------------------------------------------------------------------------
extern "C" void kernel_launch(void* const* d_in, const int* in_sizes, int n_in,
                              void* d_out, int out_size, void* d_ws,
                              size_t ws_size, hipStream_t stream) {
  const float* X = (const float*)d_in[0];
  const float* W1 = (const float*)d_in[1];
  const float* W2 = (const float*)d_in[2];
  const float* W3 = (const float*)d_in[3];
  const float* W4 = (const float*)d_in[4];
  float* out = (float*)d_out;

  char* ws = (char*)d_ws;
  unsigned int* cnt = (unsigned int*)ws;               // 256 B
  float* Z = (float*)(ws + 256);                       // 65,536,000 B
  unsigned long long* Ma =
      (unsigned long long*)(ws + 256 + 65536000ull);   // 2,048,000 B
  unsigned long long* Mb = Ma + 256000ull;             // 2,048,000 B
  unsigned long long* Min = Mb + 256000ull;            // 512,000 B
  float* Wt1 = (float*)(Min + 64000ull);               // 20,480 B (16B-align)
  float* Wt2 = Wt1 + 5120;                             // 262,144 B
  float* Wt3 = Wt2 + 65536;                            // 262,144 B
  float* Wt4 = Wt3 + 65536;                            // 65,536 B

  prep_all<<<846, 256, 0, stream>>>(X, W1, W2, W3, W4, Min, Wt1, Wt2, Wt3,
                                    Wt4, cnt);

  // layer 1: K=20 (KC=1), O=256 in two 128-halves
  spmm<20, 1, 128, 2><<<dim3(128, 2), 1024, 0, stream>>>(
      Min, Wt1, Z, 256, 256, 256, 500);
  cuba_kernel<false><<<256, 64, 0, stream>>>(Z, Ma, nullptr, cnt + 0, 256,
                                             16384);
  // layer 2
  spmm<256, 4, 128, 2><<<dim3(128, 2), 1024, 0, stream>>>(
      Ma, Wt2, Z, 256, 256, 256, 500);
  cuba_kernel<false><<<256, 64, 0, stream>>>(Z, Mb, nullptr, cnt + 1, 256,
                                             16384);
  // layer 3
  spmm<256, 4, 128, 2><<<dim3(128, 2), 1024, 0, stream>>>(
      Mb, Wt3, Z, 256, 256, 256, 500);
  cuba_kernel<false><<<256, 64, 0, stream>>>(Z, Ma, nullptr, cnt + 2, 256,
                                             16384);
  // layer 4: O=35 (padded 64), single half, PO=1
  spmm<256, 4, 64, 1><<<dim3(256, 1), 1024, 0, stream>>>(
      Ma, Wt4, Z, 64, 35, 35, 250);
  cuba_kernel<true><<<35, 64, 0, stream>>>(Z, nullptr, out, cnt + 3, 35, 2240);
  finalize_counts<<<1, 64, 0, stream>>>(cnt, out + 2240000);
}

// Round 6
// 605.394 us; speedup vs baseline: 1.0634x; 1.0634x over previous
//
#include <hip/hip_runtime.h>
#include <cstdint>
#include <cstddef>

#define TT 1000
#define NB 64000  // B*T

// ---------------------------------------------------------------------------
// NUMERICS CONTRACT: each z[n,o] is ONE ascending-k fp32 chain matching
// fmaf(s_k, W[k,o], acc), s_k in {0,1}. Exact identities used:
//   fmaf(1,W,acc) == W + acc   (single rounding, identical)
//   fmaf(0,W,acc) == acc       (bitwise; acc is never -0: chain starts +0,
//                               RN exact-cancel gives +0)
// => iterating ONLY active k ascending with v_add_f32 is bit-identical.
// Do not reorder k, do not tree-reduce.
//
// LEDGER: dense r0-r4: busy-work invariant ~72us/gemm, ~30% idle immovable.
// r5 sparse: correct, density ~35% (A~90/256 from VALU math), but spmm
// latency-bound: 145 cyc/k per wave, 1 LDS load in flight, VALUBusy 25%.
// r6: batch-4 scalar bit-extract (s_ff1 x4, wave-uniform) -> 4 independent
// ds_read_b64 in flight per wave; popcount>=4 fast path (uniform branch,
// no selects); <=3 tail = r5's proven serial loop. Masks in SGPR via
// readfirstlane.
// ---------------------------------------------------------------------------

// ---------------------------------------------------------------------------
// Sparse GEMM: Z[r, bo:bo+OH] = sum_{k in mask(r)} Wlds[k, :]  (ascending k)
// Block: 1024 thr = 16 waves, one row per wave at a time. W tile K x OH f32
// in LDS, loaded once. Masks: KC u64 words per row, bit i of word c = k
// (c*64+i) active.
// ---------------------------------------------------------------------------
template <int K, int KC, int OH, int PO>
__global__ __launch_bounds__(1024) void spmm(
    const unsigned long long* __restrict__ M, const float* __restrict__ Wt,
    float* __restrict__ Z, int Wld, int Zld, int Ostore, int rowsPerBlock) {
  __shared__ float Wl[K * OH];
  const int tid = threadIdx.x;
  const int lane = tid & 63;
  const int bo = blockIdx.y * OH;
  const int lo2 = lane * PO;

  // one-time W tile load (L2-resident source; grid reuses it)
  for (int i = tid; i < K * OH / 4; i += 1024) {
    int k = i / (OH / 4);
    int off = i - k * (OH / 4);
    *(float4*)&Wl[i * 4] = *(const float4*)&Wt[(size_t)k * Wld + bo + off * 4];
  }
  __syncthreads();

  const int wv = __builtin_amdgcn_readfirstlane(tid >> 6);
  const int r0 = blockIdx.x * rowsPerBlock;
  const int rend = r0 + rowsPerBlock;
  for (int r = r0 + wv; r < rend; r += 16) {
    const unsigned long long* mrow = M + (size_t)r * KC;
    // hoist all mask words to SGPRs (wave-uniform row => uniform masks)
    unsigned long long ms[KC];
#pragma unroll
    for (int c = 0; c < KC; c++) {
      unsigned long long mv = mrow[c];
      unsigned mlo = __builtin_amdgcn_readfirstlane((unsigned)mv);
      unsigned mhi = __builtin_amdgcn_readfirstlane((unsigned)(mv >> 32));
      ms[c] = ((unsigned long long)mhi << 32) | mlo;
    }
    float acc0 = 0.f, acc1 = 0.f;
#pragma unroll
    for (int c = 0; c < KC; c++) {
      unsigned long long m = ms[c];
      const float* Wb = &Wl[c * 64 * OH];
      int pc = __builtin_popcountll(m);
      // fast path: 4 ascending bits per iteration, 4 LDS loads in flight
      while (pc >= 4) {
        int k0 = __builtin_ctzll(m); m &= m - 1;
        int k1 = __builtin_ctzll(m); m &= m - 1;
        int k2 = __builtin_ctzll(m); m &= m - 1;
        int k3 = __builtin_ctzll(m); m &= m - 1;
        pc -= 4;
        if (PO == 2) {
          float2 w0 = *(const float2*)&Wb[k0 * OH + lo2];
          float2 w1 = *(const float2*)&Wb[k1 * OH + lo2];
          float2 w2 = *(const float2*)&Wb[k2 * OH + lo2];
          float2 w3 = *(const float2*)&Wb[k3 * OH + lo2];
          acc0 += w0.x; acc1 += w0.y;   // ascending k, order sacred
          acc0 += w1.x; acc1 += w1.y;
          acc0 += w2.x; acc1 += w2.y;
          acc0 += w3.x; acc1 += w3.y;
        } else {
          float w0 = Wb[k0 * OH + lo2];
          float w1 = Wb[k1 * OH + lo2];
          float w2 = Wb[k2 * OH + lo2];
          float w3 = Wb[k3 * OH + lo2];
          acc0 += w0; acc0 += w1; acc0 += w2; acc0 += w3;
        }
      }
      // tail (<=3): r5's proven serial loop
      while (m) {
        int kp = __builtin_ctzll(m);
        m &= m - 1;
        const float* wp = &Wb[kp * OH + lo2];
        acc0 += wp[0];
        if (PO == 2) acc1 += wp[1];
      }
    }
    int o0 = bo + lo2;
    float* zp = Z + (size_t)r * Zld + o0;
    if (PO == 2) {
      *(float2*)zp = make_float2(acc0, acc1);
    } else {
      if (o0 < Ostore) zp[0] = acc0;
    }
  }
}

// ---------------------------------------------------------------------------
// CUBA LIF recurrence (r12 pipeline: depth-2 x U=25, 50 outstanding loads).
// Exact per-step fp32 mul/add chain. Mid layers emit SPIKE BITMASKS:
// one u64 per wave per t via __ballot (bit i = lane i = o = chunk*64+i).
// ---------------------------------------------------------------------------
template <bool FINAL>
__global__ __launch_bounds__(64) void cuba_kernel(
    const float* __restrict__ Z, unsigned long long* __restrict__ Mout,
    float* __restrict__ Fout, unsigned int* __restrict__ cnt, int O,
    int total) {
  int gid = blockIdx.x * 64 + threadIdx.x;
  const int mchunk = blockIdx.x & 3;  // o-chunk within 256 (non-final only)
  unsigned int c = 0;
  if (gid < total) {
    int b = gid / O;
    int o = gid - b * O;
    const int nb = b * TT;
    const float* zp = Z + (size_t)nb * O + o;
    float* fp = Fout + ((size_t)b * O + o) * TT;
    float cur = 0.f, volt = 0.f;
    constexpr int U = 25;
    float z0[U], z1[U];

#define LOADB(buf, tbase)                         \
  _Pragma("unroll") for (int u = 0; u < U; u++) { \
    buf[u] = zp[(size_t)((tbase) + u) * O];       \
  }
#define COMPB(buf, tbase)                                              \
  _Pragma("unroll") for (int u = 0; u < U; u++) {                      \
    cur = __fadd_rn(__fmul_rn(0.75f, cur), buf[u]);                    \
    volt = __fadd_rn(__fmul_rn(0.97f, volt), cur);                     \
    bool fire = volt >= 1.25f;                                         \
    volt = fire ? 0.f : volt;                                          \
    c += fire ? 1u : 0u;                                               \
    if (FINAL) {                                                       \
      fp[(tbase) + u] = fire ? 1.f : 0.f;                              \
    } else {                                                           \
      unsigned long long mm = __ballot(fire);                          \
      if (threadIdx.x == 0)                                            \
        Mout[(size_t)(nb + (tbase) + u) * 4 + mchunk] = mm;            \
    }                                                                  \
  }

    LOADB(z0, 0)
    for (int i = 0; i < 20; i++) {
      const int base = i * 2 * U;
      LOADB(z1, base + U)
      COMPB(z0, base)
      if (i < 19) LOADB(z0, base + 2 * U)
      COMPB(z1, base + U)
    }
#undef LOADB
#undef COMPB
  }
#pragma unroll
  for (int off = 32; off; off >>= 1) c += __shfl_down(c, off, 64);
  if ((threadIdx.x & 63) == 0) atomicAdd(cnt, c);
}

// ---------------------------------------------------------------------------
// Fused prep: cnt zero + input bitmask + 4 weight transposes.
// ---------------------------------------------------------------------------
__device__ __forceinline__ void prep_w_item(const float* __restrict__ W,
                                            float* __restrict__ Wt, int O,
                                            int K, int Opad, int i) {
  int k = i / Opad, o = i - k * Opad;
  Wt[i] = (k < K && o < O) ? W[(size_t)o * K + k] : 0.f;
}

__global__ __launch_bounds__(256) void prep_all(
    const float* __restrict__ X, const float* __restrict__ W1,
    const float* __restrict__ W2, const float* __restrict__ W3,
    const float* __restrict__ W4, unsigned long long* __restrict__ Min,
    float* __restrict__ Wt1, float* __restrict__ Wt2,
    float* __restrict__ Wt3, float* __restrict__ Wt4,
    unsigned int* __restrict__ cnt) {
  const int blk = blockIdx.x;
  const int tid = threadIdx.x;
  if (blk == 0 && tid < 8) cnt[tid] = 0u;
  if (blk < 250) {
    int gid = blk * 256 + tid;  // n
    unsigned long long msk = 0ull;
#pragma unroll
    for (int ch = 0; ch < 20; ch++) {
      float v = X[((size_t)(gid / TT) * 20 + ch) * TT + (gid % TT)];
      msk |= (unsigned long long)(v != 0.f ? 1u : 0u) << ch;
    }
    Min[gid] = msk;
  } else if (blk < 270) {  // W1t [20][256]: 5120 items
    prep_w_item(W1, Wt1, 256, 20, 256, (blk - 250) * 256 + tid);
  } else if (blk < 526) {  // W2t [256][256]
    prep_w_item(W2, Wt2, 256, 256, 256, (blk - 270) * 256 + tid);
  } else if (blk < 782) {  // W3t [256][256]
    prep_w_item(W3, Wt3, 256, 256, 256, (blk - 526) * 256 + tid);
  } else {                 // W4t [256][64]: 16384 items
    prep_w_item(W4, Wt4, 35, 256, 64, (blk - 782) * 256 + tid);
  }
}

__global__ void finalize_counts(const unsigned int* __restrict__ cnt,
                                float* __restrict__ out) {
  int i = threadIdx.x;
  if (i < 4) {
    const float denom[4] = {16384000.f, 16384000.f, 16384000.f, 2240000.f};
    out[i] = (float)cnt[i] / denom[i];
  }
}

// ---------------------------------------------------------------------------
extern "C" void kernel_launch(void* const* d_in, const int* in_sizes, int n_in,
                              void* d_out, int out_size, void* d_ws,
                              size_t ws_size, hipStream_t stream) {
  const float* X = (const float*)d_in[0];
  const float* W1 = (const float*)d_in[1];
  const float* W2 = (const float*)d_in[2];
  const float* W3 = (const float*)d_in[3];
  const float* W4 = (const float*)d_in[4];
  float* out = (float*)d_out;

  char* ws = (char*)d_ws;
  unsigned int* cnt = (unsigned int*)ws;               // 256 B
  float* Z = (float*)(ws + 256);                       // 65,536,000 B
  unsigned long long* Ma =
      (unsigned long long*)(ws + 256 + 65536000ull);   // 2,048,000 B
  unsigned long long* Mb = Ma + 256000ull;             // 2,048,000 B
  unsigned long long* Min = Mb + 256000ull;            // 512,000 B
  float* Wt1 = (float*)(Min + 64000ull);               // 20,480 B (16B-align)
  float* Wt2 = Wt1 + 5120;                             // 262,144 B
  float* Wt3 = Wt2 + 65536;                            // 262,144 B
  float* Wt4 = Wt3 + 65536;                             // 65,536 B

  prep_all<<<846, 256, 0, stream>>>(X, W1, W2, W3, W4, Min, Wt1, Wt2, Wt3,
                                    Wt4, cnt);

  // layer 1: K=20 (KC=1), O=256 in two 128-halves
  spmm<20, 1, 128, 2><<<dim3(128, 2), 1024, 0, stream>>>(
      Min, Wt1, Z, 256, 256, 256, 500);
  cuba_kernel<false><<<256, 64, 0, stream>>>(Z, Ma, nullptr, cnt + 0, 256,
                                             16384);
  // layer 2
  spmm<256, 4, 128, 2><<<dim3(128, 2), 1024, 0, stream>>>(
      Ma, Wt2, Z, 256, 256, 256, 500);
  cuba_kernel<false><<<256, 64, 0, stream>>>(Z, Mb, nullptr, cnt + 1, 256,
                                             16384);
  // layer 3
  spmm<256, 4, 128, 2><<<dim3(128, 2), 1024, 0, stream>>>(
      Mb, Wt3, Z, 256, 256, 256, 500);
  cuba_kernel<false><<<256, 64, 0, stream>>>(Z, Ma, nullptr, cnt + 2, 256,
                                             16384);
  // layer 4: O=35 (padded 64), single half, PO=1
  spmm<256, 4, 64, 1><<<dim3(256, 1), 1024, 0, stream>>>(
      Ma, Wt4, Z, 64, 35, 35, 250);
  cuba_kernel<true><<<35, 64, 0, stream>>>(Z, nullptr, out, cnt + 3, 35, 2240);
  finalize_counts<<<1, 64, 0, stream>>>(cnt, out + 2240000);
}